// Round 13
// baseline (114.379 us; speedup 1.0000x reference)
//
#include <hip/hip_runtime.h>

typedef __attribute__((ext_vector_type(8))) short short8;
typedef __attribute__((ext_vector_type(4))) float f32x4;

#define DEVI __device__ __forceinline__

static constexpr int HIDDEN   = 2048;
static constexpr int NHEADS   = 16;
static constexpr int NKV      = 8;
static constexpr int HDIM     = 128;
static constexpr int QLEN     = 2048;
static constexpr int KVLEN    = 4096;
static constexpr int ENCLEN   = 512;
static constexpr int NREQ     = 8;
static constexpr float SCALING = 0.0625f;   // 256^-0.5
static constexpr float EPS     = 1e-6f;

DEVI unsigned short f2bf(float f) {
  unsigned int b = __float_as_uint(f);
  b += 0x7FFFu + ((b >> 16) & 1u);          // RNE
  return (unsigned short)(b >> 16);
}

DEVI void g2l16(const void* g, void* l) {
  __builtin_amdgcn_global_load_lds(
      (const __attribute__((address_space(1))) void*)g,
      (__attribute__((address_space(3))) void*)l, 16, 0, 0);
}

// ---------------- fused fp32 -> bf16 convert of all three inputs ----------------
__global__ __launch_bounds__(256) void cvt_all(const float* __restrict__ h,
                                               const float* __restrict__ e,
                                               const float* __restrict__ w,
                                               unsigned short* __restrict__ hb,
                                               unsigned short* __restrict__ eb,
                                               unsigned short* __restrict__ wb) {
  constexpr long S1 = (long)2048 * 2048, S2 = (long)4096 * 2048;
  long i = ((long)blockIdx.x * 256 + threadIdx.x) * 8;
  const float* src;
  unsigned short* dst;
  if (i < S1)           { src = h + i;            dst = hb + i; }
  else if (i < S1 + S2) { src = e + (i - S1);     dst = eb + (i - S1); }
  else                  { src = w + (i - S1 - S2); dst = wb + (i - S1 - S2); }
  float4 a = *(const float4*)src;
  float4 b = *(const float4*)(src + 4);
  short8 o;
  o[0] = (short)f2bf(a.x); o[1] = (short)f2bf(a.y);
  o[2] = (short)f2bf(a.z); o[3] = (short)f2bf(a.w);
  o[4] = (short)f2bf(b.x); o[5] = (short)f2bf(b.y);
  o[6] = (short)f2bf(b.z); o[7] = (short)f2bf(b.w);
  *(short8*)dst = o;
}

// ================= 256x256 GEMM: BK=64, dbuf-2, FINE 4-phase schedule ==========
// LDS: 2 bufs x {A halves [128][64] x2, B halves [128][64] x2} = 8 x 16KB = 128KB.
// Per K-tile kt (buf cb=kt&1):
//   top: burst-stage ALL of kt+1 (8 gloads -> buf cb^1)
//   ph0: ds_read A(quadM0,12=8A+4B) | bar | 16 MFMA (M0N0) setprio | bar
//   ph1: ds_read B(N1,4)            | bar | 16 MFMA (M0N1)         | bar
//   ph2: ds_read A(M1)+B(N0)        | bar | 16 MFMA (M1N0)         | bar
//   ph3: ds_read B(N1,4)            | bar | 16 MFMA (M1N1)         | vmcnt(0) bar
// Guards: kt+1's gloads issued at kt top, waited at kt end (4 phases ~2400cyc
// > HBM latency -> free). WAR: gloads target buf cb^1, whose reads (kt-1)
// drained before kt's top barrier. NO manual lgkmcnt: compiler emits
// fine-grained waits inside each small phase (m141/m196 lesson).

#define SBAR  __builtin_amdgcn_s_barrier()

DEVI short8 rdfrag(const char* half, int row, int g) {   // g = k-granule 0..7
  return *(const short8*)(half + row * 128 + ((g ^ (row & 7)) << 4));
}

__global__ __launch_bounds__(512, 2) void gemm_qkv8(
    const unsigned short* __restrict__ Adec, const unsigned short* __restrict__ Aenc,
    const unsigned short* __restrict__ Bw,
    const float* __restrict__ q_nw, const float* __restrict__ k_nw,
    unsigned short* __restrict__ q_bf, unsigned short* __restrict__ k_bf,
    unsigned short* __restrict__ v_t) {
  extern __shared__ char lds[];
  const int K = 2048, NKT = 32;   // 32 K-tiles of 64

  // bijective XCD-chunked swizzle over 192 = 8*24 blocks
  int flat = blockIdx.y * 8 + blockIdx.x;
  int swz = (flat & 7) * 24 + (flat >> 3);
  int bx = swz & 7, by = swz >> 3;

  const unsigned short* A;
  int bm0;
  if (by < 8) { A = Adec; bm0 = by * 256; }
  else        { A = Aenc; bm0 = (by - 8) * 256; }
  const unsigned short* Bp = Bw + (by < 8 ? 0 : (size_t)2048 * 2048);
  const int bn0 = bx * 256;

  const int tid = threadIdx.x, lane = tid & 63, wave = tid >> 6;
  const int lr = lane & 15, lg = lane >> 4;
  const int wr = wave >> 2, wc = wave & 3;   // 2M x 4N
  const int bcol0 = (wc & 1) * 64;           // col base within B-half (wc>>1)

#define AH(b, h) (lds + (b) * 65536 + (h) * 16384)
#define BH(b, h) (lds + (b) * 65536 + 32768 + (h) * 16384)

  // stage mapping: 2 chunks per half-tile; chunk c = i*512+tid, dest byte c*16
  // dest (row=c>>3, g'=c&7) <- source granule g = g' ^ (row&7)
  int srow[2], scol[2];
#pragma unroll
  for (int i = 0; i < 2; ++i) {
    int c = i * 512 + tid;
    srow[i] = c >> 3;
    scol[i] = ((c & 7) ^ ((c >> 3) & 7)) * 8;
  }

#define STG_KT(kt)                                                            \
  {                                                                           \
    const int b_ = (kt) & 1;                                                  \
    const size_t kb_ = (size_t)(kt) * 64;                                     \
    _Pragma("unroll") for (int i = 0; i < 2; ++i) {                           \
      const int d_ = (i * 512 + tid) * 16;                                    \
      g2l16(A  + (size_t)(bm0 + srow[i]) * K + kb_ + scol[i],       AH(b_, 0) + d_); \
      g2l16(A  + (size_t)(bm0 + 128 + srow[i]) * K + kb_ + scol[i], AH(b_, 1) + d_); \
      g2l16(Bp + (size_t)(bn0 + srow[i]) * K + kb_ + scol[i],       BH(b_, 0) + d_); \
      g2l16(Bp + (size_t)(bn0 + 128 + srow[i]) * K + kb_ + scol[i], BH(b_, 1) + d_); \
    }                                                                         \
  }

  f32x4 acc[8][4] = {};
  short8 a[4][2], b[2][2];

#define LOAD_A(buf, qm)                                                       \
  {                                                                           \
    const char* ah = AH(buf, wr);                                             \
    _Pragma("unroll") for (int m = 0; m < 4; ++m)                             \
        _Pragma("unroll") for (int kk = 0; kk < 2; ++kk)                      \
            a[m][kk] = rdfrag(ah, (qm) * 64 + m * 16 + lr, kk * 4 + lg);      \
  }
#define LOAD_B(buf, qn)                                                       \
  {                                                                           \
    const char* bh = BH(buf, wc >> 1);                                        \
    _Pragma("unroll") for (int n = 0; n < 2; ++n)                             \
        _Pragma("unroll") for (int kk = 0; kk < 2; ++kk)                      \
            b[n][kk] = rdfrag(bh, bcol0 + (qn) * 32 + n * 16 + lr, kk * 4 + lg); \
  }
#define MM16(qm, qn)                                                          \
  {                                                                           \
    __builtin_amdgcn_s_setprio(1);                                            \
    _Pragma("unroll") for (int m = 0; m < 4; ++m)                             \
        _Pragma("unroll") for (int n = 0; n < 2; ++n)                         \
            _Pragma("unroll") for (int kk = 0; kk < 2; ++kk)                  \
                acc[(qm)*4 + m][(qn)*2 + n] =                                 \
                    __builtin_amdgcn_mfma_f32_16x16x32_bf16(                  \
                        a[m][kk], b[n][kk], acc[(qm)*4 + m][(qn)*2 + n], 0, 0, 0); \
    __builtin_amdgcn_s_setprio(0);                                            \
  }

  // ---- prologue: stage K-tile 0, wait, publish ----
  STG_KT(0);
  asm volatile("s_waitcnt vmcnt(0)" ::: "memory");
  SBAR;

#pragma unroll 2
  for (int kt = 0; kt < NKT; ++kt) {
    const int cb = kt & 1;
    if (kt + 1 < NKT) STG_KT(kt + 1);
    LOAD_A(cb, 0); LOAD_B(cb, 0); SBAR; MM16(0, 0); SBAR;   // ph0
    LOAD_B(cb, 1);                SBAR; MM16(0, 1); SBAR;   // ph1
    LOAD_A(cb, 1); LOAD_B(cb, 0); SBAR; MM16(1, 0); SBAR;   // ph2
    LOAD_B(cb, 1);                SBAR; MM16(1, 1);         // ph3
    if (kt + 1 < NKT) asm volatile("s_waitcnt vmcnt(0)" ::: "memory");
    SBAR;
  }

  // ================= fused epilogue (unchanged) =================
  const int btype = (by < 8) ? 0 : (bx < 4 ? 1 : 2);  // 0=Q,1=K,2=V
  const int tokbase0 = (by < 8 ? by : by - 8) * 256;

  if (btype < 2) {
    float* Lf = (float*)lds;                 // [64][260] f32
    const float* wnorm = (btype == 0) ? q_nw : k_nw;
    const float fscale = (btype == 0) ? SCALING : 1.0f;
    unsigned short* dst = (btype == 0) ? q_bf : k_bf;
    const size_t LEN = (btype == 0) ? (size_t)QLEN : (size_t)KVLEN;
    const int dloc = lr * 8;
    float wv[8];
#pragma unroll
    for (int j = 0; j < 8; ++j) wv[j] = 1.0f + wnorm[dloc + j];

#pragma unroll
    for (int q = 0; q < 4; ++q) {
      SBAR;
      if (wr == (q >> 1)) {
        const int amb = (q & 1) * 4;
#pragma unroll
        for (int am2 = 0; am2 < 4; ++am2)
#pragma unroll
          for (int n = 0; n < 4; ++n)
#pragma unroll
            for (int r = 0; r < 4; ++r)
              Lf[(am2 * 16 + lg * 4 + r) * 260 + wc * 64 + n * 16 + lr] =
                  acc[amb + am2][n][r];
      }
      SBAR;
#pragma unroll
      for (int it = 0; it < 4; ++it) {
        int pair = it * 32 + wave * 4 + (lane >> 4);   // 0..127
        int row = pair >> 1, hh = pair & 1;
        const float* src = &Lf[row * 260 + hh * 128 + dloc];
        f32x4 x0 = *(const f32x4*)src;
        f32x4 x1 = *(const f32x4*)(src + 4);
        float ssq = x0[0]*x0[0] + x0[1]*x0[1] + x0[2]*x0[2] + x0[3]*x0[3] +
                    x1[0]*x1[0] + x1[1]*x1[1] + x1[2]*x1[2] + x1[3]*x1[3];
#pragma unroll
        for (int m = 8; m >= 1; m >>= 1) ssq += __shfl_xor(ssq, m);
        float sc = rsqrtf(ssq * (1.0f / 128.0f) + EPS) * fscale;
        short8 o;
        o[0] = (short)f2bf(x0[0] * sc * wv[0]); o[1] = (short)f2bf(x0[1] * sc * wv[1]);
        o[2] = (short)f2bf(x0[2] * sc * wv[2]); o[3] = (short)f2bf(x0[3] * sc * wv[3]);
        o[4] = (short)f2bf(x1[0] * sc * wv[4]); o[5] = (short)f2bf(x1[1] * sc * wv[5]);
        o[6] = (short)f2bf(x1[2] * sc * wv[6]); o[7] = (short)f2bf(x1[3] * sc * wv[7]);
        int tok = tokbase0 + q * 64 + row;
        int hd = 2 * bx + hh;
        *(short8*)&dst[((size_t)hd * LEN + tok) * 128 + dloc] = o;
      }
    }
  } else {
    float* Lv = (float*)lds;                 // [256 d][68] f32 (col-major quarter)
#pragma unroll
    for (int q = 0; q < 4; ++q) {
      SBAR;
      if (wr == (q >> 1)) {
        const int amb = (q & 1) * 4;
#pragma unroll
        for (int am2 = 0; am2 < 4; ++am2)
#pragma unroll
          for (int n = 0; n < 4; ++n)
            *(f32x4*)&Lv[(wc * 64 + n * 16 + lr) * 68 + am2 * 16 + lg * 4] =
                acc[amb + am2][n];
      }
      SBAR;
      int d = tid >> 1, th = tid & 1;        // d 0..255, token half
      const float* src = &Lv[d * 68 + th * 32];
      int kh = (bx - 4) * 2 + (d >> 7);
      int tok = tokbase0 + q * 64 + th * 32;
      unsigned short* vp = &v_t[((size_t)kh * 128 + (d & 127)) * KVLEN + tok];
#pragma unroll
      for (int j = 0; j < 4; ++j) {
        f32x4 v0 = *(const f32x4*)(src + j * 8);
        f32x4 v1 = *(const f32x4*)(src + j * 8 + 4);
        short8 o;
        o[0] = (short)f2bf(v0[0]); o[1] = (short)f2bf(v0[1]);
        o[2] = (short)f2bf(v0[2]); o[3] = (short)f2bf(v0[3]);
        o[4] = (short)f2bf(v1[0]); o[5] = (short)f2bf(v1[1]);
        o[6] = (short)f2bf(v1[2]); o[7] = (short)f2bf(v1[3]);
        *(short8*)(vp + j * 8) = o;
      }
    }
  }
#undef AH
#undef BH
#undef STG_KT
#undef LOAD_A
#undef LOAD_B
#undef MM16
}

// ---------------- attention: K/V chunk double-buffer, 1 barrier/chunk ----------------
__global__ __launch_bounds__(256, 4) void attn_kernel(
    const unsigned short* __restrict__ qb,   // [16][2048][128]
    const unsigned short* __restrict__ kb,   // [8][4096][128]
    const unsigned short* __restrict__ vt,   // [8][128][4096]
    const int* __restrict__ seq_lens,
    float* __restrict__ out) {               // [2048][2048]
  __shared__ __align__(16) char smem[73728];

  const int h = blockIdx.y;
  const int t0 = blockIdx.x * 64;
  int req = 0, qs = 0;
#pragma unroll 1
  while (req < NREQ - 1 && qs + seq_lens[req] <= t0) { qs += seq_lens[req]; ++req; }
  const int slen = seq_lens[req];
  const int rows = min(64, qs + slen - t0);
  if (rows <= 0) return;
  const int qbase = t0;

  const int tid = threadIdx.x, lane = tid & 63, wave = tid >> 6;
  const int lr = lane & 15, lg = lane >> 4;
  const int m0w = wave * 16;
  const int kh = h >> 1;
  const int kv0 = req * ENCLEN;

#define STAGE_K(c, db)                                                        \
  _Pragma("unroll") for (int i = 0; i < 4; ++i) {                             \
    int idx = i * 256 + tid;                                                  \
    int row = idx >> 4, slot = idx & 15;                                      \
    g2l16(kb + ((size_t)kh * KVLEN + kv0 + (c) * 64 + row) * 128 +            \
              ((slot ^ (row & 15)) << 3),                                     \
          smem + (db) * 16384 + idx * 16);                                    \
  }
#define STAGE_V(c, db)                                                        \
  _Pragma("unroll") for (int i = 0; i < 4; ++i) {                             \
    int idx = i * 256 + tid;                                                  \
    int row = idx >> 3, slot = idx & 7;                                       \
    g2l16(vt + ((size_t)kh * 128 + row) * KVLEN + kv0 + (c) * 64 +            \
              ((slot ^ (row & 7)) << 3),                                      \
          smem + 32768 + (db) * 16384 + idx * 16);                            \
  }

  unsigned short* Ps = (unsigned short*)(smem + 65536);

  short8 a_q[4];
  {
    int qr = qbase + min(m0w + lr, rows - 1);
    const unsigned short* qp = qb + ((size_t)h * QLEN + qr) * 128 + lg * 8;
#pragma unroll
    for (int ks = 0; ks < 4; ++ks) a_q[ks] = *(const short8*)(qp + ks * 32);
  }

  f32x4 acc[8] = {};
  float mrow[4], lsum[4];
#pragma unroll
  for (int r = 0; r < 4; ++r) { mrow[r] = -1e30f; lsum[r] = 0.f; }

  STAGE_K(0, 0); STAGE_V(0, 0);

  int cb = 0;
#pragma unroll 1
  for (int c = 0; c < 8; ++c) {
    asm volatile("s_waitcnt vmcnt(0)" ::: "memory");
    __syncthreads();
    if (c < 7) { STAGE_K(c + 1, cb ^ 1); STAGE_V(c + 1, cb ^ 1); }
    const unsigned short* Kb = (const unsigned short*)(smem + cb * 16384);
    const unsigned short* Vb = (const unsigned short*)(smem + 32768 + cb * 16384);

    f32x4 s[4] = {};
#pragma unroll
    for (int ks = 0; ks < 4; ++ks) {
      short8 bk[4];
#pragma unroll
      for (int n = 0; n < 4; ++n) {
        int row = n * 16 + lr;
        bk[n] = *(const short8*)&Kb[row * 128 + (((ks * 4 + lg) ^ (row & 15)) << 3)];
      }
#pragma unroll
      for (int n = 0; n < 4; ++n)
        s[n] = __builtin_amdgcn_mfma_f32_16x16x32_bf16(a_q[ks], bk[n], s[n], 0, 0, 0);
    }

#pragma unroll
    for (int r = 0; r < 4; ++r) {
      float mx = fmaxf(fmaxf(s[0][r], s[1][r]), fmaxf(s[2][r], s[3][r]));
#pragma unroll
      for (int msk = 8; msk >= 1; msk >>= 1) mx = fmaxf(mx, __shfl_xor(mx, msk));
      float mnew = fmaxf(mrow[r], mx);
      float al = __expf(mrow[r] - mnew);
      mrow[r] = mnew;
      float rs = 0.f;
#pragma unroll
      for (int n = 0; n < 4; ++n) {
        float p = __expf(s[n][r] - mnew);
        s[n][r] = p;
        rs += p;
      }
#pragma unroll
      for (int msk = 8; msk >= 1; msk >>= 1) rs += __shfl_xor(rs, msk);
      lsum[r] = lsum[r] * al + rs;
#pragma unroll
      for (int n2 = 0; n2 < 8; ++n2) acc[n2][r] *= al;
    }

#pragma unroll
    for (int n = 0; n < 4; ++n)
#pragma unroll
      for (int r = 0; r < 4; ++r) {
        int row = m0w + lg * 4 + r;
        int col = n * 16 + lr;
        Ps[row * 64 + (col ^ ((row & 7) << 3))] = f2bf(s[n][r]);
      }
    asm volatile("s_waitcnt lgkmcnt(0)" ::: "memory");
    __builtin_amdgcn_sched_barrier(0);

#pragma unroll
    for (int ks = 0; ks < 2; ++ks) {
      int prow = m0w + lr;
      short8 pa = *(const short8*)&Ps[prow * 64 + (((ks * 4 + lg) ^ (prow & 7)) << 3)];
#pragma unroll
      for (int n2 = 0; n2 < 8; ++n2) {
        int row = n2 * 16 + lr;
        short8 bv = *(const short8*)&Vb[row * 64 + (((ks * 4 + lg) ^ (row & 7)) << 3)];
        acc[n2] = __builtin_amdgcn_mfma_f32_16x16x32_bf16(pa, bv, acc[n2], 0, 0, 0);
      }
    }
    cb ^= 1;
  }
  __syncthreads();

  float inv[4];
#pragma unroll
  for (int r = 0; r < 4; ++r) inv[r] = 1.0f / lsum[r];
#pragma unroll
  for (int n2 = 0; n2 < 8; ++n2)
#pragma unroll
    for (int r = 0; r < 4; ++r) acc[n2][r] *= inv[r];

  constexpr int OFS = 132;
  float* Of = (float*)smem;
#pragma unroll
  for (int n2 = 0; n2 < 8; ++n2)
#pragma unroll
    for (int r = 0; r < 4; ++r)
      Of[(m0w + lg * 4 + r) * OFS + n2 * 16 + lr] = acc[n2][r];
  __syncthreads();
#pragma unroll
  for (int p = 0; p < 8; ++p) {
    int idx = p * 256 + tid;
    int row = idx >> 5, c4 = (idx & 31) * 4;
    if (row < rows) {
      f32x4 v = *(const f32x4*)&Of[row * OFS + c4];
      *(f32x4*)&out[(size_t)(qbase + row) * 2048 + h * 128 + c4] = v;
    }
  }
#undef STAGE_K
#undef STAGE_V
}

// ---------------- launch ----------------
extern "C" void kernel_launch(void* const* d_in, const int* in_sizes, int n_in,
                              void* d_out, int out_size, void* d_ws, size_t ws_size,
                              hipStream_t stream) {
  const float* hidden = (const float*)d_in[0];
  const float* enc    = (const float*)d_in[1];
  const float* w_qkv  = (const float*)d_in[2];
  const float* q_nw   = (const float*)d_in[3];
  const float* k_nw   = (const float*)d_in[4];
  const int*   slens  = (const int*)d_in[5];
  float* out = (float*)d_out;

  char* ws = (char*)d_ws;
  unsigned short* h_bf = (unsigned short*)(ws + 0);           //  8.39 MB
  unsigned short* e_bf = (unsigned short*)(ws + 8388608);     // 16.78 MB
  unsigned short* w_bf = (unsigned short*)(ws + 25165824);    // 16.78 MB
  unsigned short* q_bf = (unsigned short*)(ws + 41943040);    //  8.39 MB
  unsigned short* k_bf = (unsigned short*)(ws + 50331648);    //  8.39 MB
  unsigned short* v_t  = (unsigned short*)(ws + 58720256);    //  8.39 MB (ends 67.1MB)

  static bool attr_set = false;
  if (!attr_set) {
    hipFuncSetAttribute((const void*)gemm_qkv8,
                        hipFuncAttributeMaxDynamicSharedMemorySize, 131072);
    attr_set = true;
  }

  cvt_all<<<10240, 256, 0, stream>>>(hidden, enc, w_qkv, h_bf, e_bf, w_bf);

  gemm_qkv8<<<dim3(8, 24), 512, 131072, stream>>>(h_bf, e_bf, w_bf, q_nw, k_nw,
                                                  q_bf, k_bf, v_t);

  attn_kernel<<<dim3(32, 16), 256, 0, stream>>>(q_bf, k_bf, v_t, slens, out);
}

// Round 14
// 102.055 us; speedup vs baseline: 1.1208x; 1.1208x over previous
//
#include <hip/hip_runtime.h>

typedef __attribute__((ext_vector_type(8))) short short8;
typedef __attribute__((ext_vector_type(4))) float f32x4;

#define DEVI __device__ __forceinline__

static constexpr int HIDDEN   = 2048;
static constexpr int NHEADS   = 16;
static constexpr int NKV      = 8;
static constexpr int HDIM     = 128;
static constexpr int QLEN     = 2048;
static constexpr int KVLEN    = 4096;
static constexpr int ENCLEN   = 512;
static constexpr int NREQ     = 8;
static constexpr float SCALING = 0.0625f;   // 256^-0.5
static constexpr float EPS     = 1e-6f;

DEVI unsigned short f2bf(float f) {
  unsigned int b = __float_as_uint(f);
  b += 0x7FFFu + ((b >> 16) & 1u);          // RNE
  return (unsigned short)(b >> 16);
}

DEVI void g2l16(const void* g, void* l) {
  __builtin_amdgcn_global_load_lds(
      (const __attribute__((address_space(1))) void*)g,
      (__attribute__((address_space(3))) void*)l, 16, 0, 0);
}

// ---------------- fused fp32 -> bf16 convert of all three inputs ----------------
__global__ __launch_bounds__(256) void cvt_all(const float* __restrict__ h,
                                               const float* __restrict__ e,
                                               const float* __restrict__ w,
                                               unsigned short* __restrict__ hb,
                                               unsigned short* __restrict__ eb,
                                               unsigned short* __restrict__ wb) {
  constexpr long S1 = (long)2048 * 2048, S2 = (long)4096 * 2048;
  long i = ((long)blockIdx.x * 256 + threadIdx.x) * 8;
  const float* src;
  unsigned short* dst;
  if (i < S1)           { src = h + i;            dst = hb + i; }
  else if (i < S1 + S2) { src = e + (i - S1);     dst = eb + (i - S1); }
  else                  { src = w + (i - S1 - S2); dst = wb + (i - S1 - S2); }
  float4 a = *(const float4*)src;
  float4 b = *(const float4*)(src + 4);
  short8 o;
  o[0] = (short)f2bf(a.x); o[1] = (short)f2bf(a.y);
  o[2] = (short)f2bf(a.z); o[3] = (short)f2bf(a.w);
  o[4] = (short)f2bf(b.x); o[5] = (short)f2bf(b.y);
  o[6] = (short)f2bf(b.z); o[7] = (short)f2bf(b.w);
  *(short8*)dst = o;
}

// ================= 256x256 GEMM: BK=32 subtiles, ring-3 LDS, 1 barrier/subtile ====
// (R8 structure — measured best of 7 variants: 60.2us, MfmaUtil 33%.)
// 64 subtiles of K=32. Ring slot(t) = t%3; each slot = A[2x 128rows x 32K] +
// B[2x 128rows x 32K] = 32KB; ring = 96KB. Per subtile, per wave:
//   vmcnt(4); s_barrier; ds_read A-mq0(4)+B(4); stage slot(t+2) [4 gloads];
//   16 MFMA; ds_read A-mq1(4); 16 MFMA.
// Ring proof: stage at t targets slot (t+2)%3 == slot(t-1), whose reads all
// completed before this iteration's barrier. vmcnt(4) leaves only the newest
// group outstanding -> the group for slot(t) (issued t-2) has landed.

#define SBAR  __builtin_amdgcn_s_barrier()

DEVI short8 rdfrag(const char* unit, int row, int lg) {
  int L = row >> 1;
  int g = ((row & 1) << 2) + lg;
  return *(const short8*)(unit + L * 128 + ((g ^ (L & 7)) << 4));
}

__global__ __launch_bounds__(512, 2) void gemm_qkv8(
    const unsigned short* __restrict__ Adec, const unsigned short* __restrict__ Aenc,
    const unsigned short* __restrict__ Bw,
    const float* __restrict__ q_nw, const float* __restrict__ k_nw,
    unsigned short* __restrict__ q_bf, unsigned short* __restrict__ k_bf,
    unsigned short* __restrict__ v_t) {
  extern __shared__ char lds[];
  const int K = 2048, NST = 64;   // 64 subtiles of K=32

  // XCD swizzle over 192 = 8*24
  int flat = blockIdx.y * 8 + blockIdx.x;
  int swz = (flat & 7) * 24 + (flat >> 3);
  int bx = swz & 7, by = swz >> 3;

  const unsigned short* A;
  int bm0;
  if (by < 8) { A = Adec; bm0 = by * 256; }
  else        { A = Aenc; bm0 = (by - 8) * 256; }
  const unsigned short* Bp = Bw + (by < 8 ? 0 : (size_t)2048 * 2048);
  const int bn0 = bx * 256;

  const int tid = threadIdx.x, lane = tid & 63, wave = tid >> 6;
  const int lr = lane & 15, lg = lane >> 4;
  const int wr = wave >> 2, wc = wave & 3;   // 2M x 4N
  const int bq = (wc & 1) * 64;

  // stage source mapping (linear dest chunk -> swizzled source row/col)
  const int sB = tid * 16;
  const int sL = sB >> 7, sgp = (sB >> 4) & 7;
  const int sg = sgp ^ (sL & 7);
  const int st_row = sL * 2 + (sg >> 2);
  const int st_col = (sg & 3) * 8;
  const size_t a0off = (size_t)(bm0 + st_row) * K + st_col;
  const size_t a1off = a0off + (size_t)128 * K;
  const size_t b0off = (size_t)(bn0 + st_row) * K + st_col;
  const size_t b1off = b0off + (size_t)128 * K;

#define STG4(t)                                                       \
  {                                                                   \
    const size_t kc = (size_t)(t) * 32;                               \
    char* base = lds + ((t) % 3) * 32768;                             \
    g2l16(A + a0off + kc,  base + sB);                                \
    g2l16(A + a1off + kc,  base + 8192 + sB);                         \
    g2l16(Bp + b0off + kc, base + 16384 + sB);                        \
    g2l16(Bp + b1off + kc, base + 24576 + sB);                        \
  }

  f32x4 acc[8][4] = {};

#define MM(mq, aS, bS)                                                \
  {                                                                   \
    __builtin_amdgcn_s_setprio(1);                                    \
    _Pragma("unroll") for (int m = 0; m < 4; ++m)                     \
        _Pragma("unroll") for (int n = 0; n < 4; ++n)                 \
            acc[(mq)*4 + m][n] = __builtin_amdgcn_mfma_f32_16x16x32_bf16( \
                aS[m], bS[n], acc[(mq)*4 + m][n], 0, 0, 0);           \
    __builtin_amdgcn_s_setprio(0);                                    \
  }

  // ---- prologue: stage subtiles 0,1 ----
  STG4(0); STG4(1);

#pragma unroll 3
  for (int t = 0; t < NST - 1; ++t) {
    asm volatile("s_waitcnt vmcnt(4)" ::: "memory");
    SBAR;
    const char* ua = lds + (t % 3) * 32768 + wr * 8192;
    const char* ub = lds + (t % 3) * 32768 + 16384 + ((wc >> 1) << 13);
    short8 a0[4], b0[4], a1[4];
#pragma unroll
    for (int m = 0; m < 4; ++m) a0[m] = rdfrag(ua, m * 16 + lr, lg);
#pragma unroll
    for (int n = 0; n < 4; ++n) b0[n] = rdfrag(ub, bq + n * 16 + lr, lg);
    if (t < NST - 2) STG4(t + 2);
    MM(0, a0, b0);
#pragma unroll
    for (int m = 0; m < 4; ++m) a1[m] = rdfrag(ua, 64 + m * 16 + lr, lg);
    MM(1, a1, b0);
  }
  {  // t = 63: drain
    asm volatile("s_waitcnt vmcnt(0)" ::: "memory");
    SBAR;
    const char* ua = lds + ((NST - 1) % 3) * 32768 + wr * 8192;
    const char* ub = lds + ((NST - 1) % 3) * 32768 + 16384 + ((wc >> 1) << 13);
    short8 a0[4], b0[4], a1[4];
#pragma unroll
    for (int m = 0; m < 4; ++m) a0[m] = rdfrag(ua, m * 16 + lr, lg);
#pragma unroll
    for (int n = 0; n < 4; ++n) b0[n] = rdfrag(ub, bq + n * 16 + lr, lg);
    MM(0, a0, b0);
#pragma unroll
    for (int m = 0; m < 4; ++m) a1[m] = rdfrag(ua, 64 + m * 16 + lr, lg);
    MM(1, a1, b0);
  }

  // ================= fused epilogue =================
  const int btype = (by < 8) ? 0 : (bx < 4 ? 1 : 2);  // 0=Q,1=K,2=V
  const int tokbase0 = (by < 8 ? by : by - 8) * 256;

  if (btype < 2) {
    float* Lf = (float*)lds;                 // [64][260] f32
    const float* wnorm = (btype == 0) ? q_nw : k_nw;
    const float fscale = (btype == 0) ? SCALING : 1.0f;
    unsigned short* dst = (btype == 0) ? q_bf : k_bf;
    const size_t LEN = (btype == 0) ? (size_t)QLEN : (size_t)KVLEN;
    const int dloc = lr * 8;
    float wv[8];
#pragma unroll
    for (int j = 0; j < 8; ++j) wv[j] = 1.0f + wnorm[dloc + j];

#pragma unroll
    for (int q = 0; q < 4; ++q) {
      SBAR;
      if (wr == (q >> 1)) {
        const int amb = (q & 1) * 4;
#pragma unroll
        for (int am2 = 0; am2 < 4; ++am2)
#pragma unroll
          for (int n = 0; n < 4; ++n)
#pragma unroll
            for (int r = 0; r < 4; ++r)
              Lf[(am2 * 16 + lg * 4 + r) * 260 + wc * 64 + n * 16 + lr] =
                  acc[amb + am2][n][r];
      }
      SBAR;
#pragma unroll
      for (int it = 0; it < 4; ++it) {
        int pair = it * 32 + wave * 4 + (lane >> 4);   // 0..127
        int row = pair >> 1, hh = pair & 1;
        const float* src = &Lf[row * 260 + hh * 128 + dloc];
        f32x4 x0 = *(const f32x4*)src;
        f32x4 x1 = *(const f32x4*)(src + 4);
        float ssq = x0[0]*x0[0] + x0[1]*x0[1] + x0[2]*x0[2] + x0[3]*x0[3] +
                    x1[0]*x1[0] + x1[1]*x1[1] + x1[2]*x1[2] + x1[3]*x1[3];
#pragma unroll
        for (int m = 8; m >= 1; m >>= 1) ssq += __shfl_xor(ssq, m);
        float sc = rsqrtf(ssq * (1.0f / 128.0f) + EPS) * fscale;
        short8 o;
        o[0] = (short)f2bf(x0[0] * sc * wv[0]); o[1] = (short)f2bf(x0[1] * sc * wv[1]);
        o[2] = (short)f2bf(x0[2] * sc * wv[2]); o[3] = (short)f2bf(x0[3] * sc * wv[3]);
        o[4] = (short)f2bf(x1[0] * sc * wv[4]); o[5] = (short)f2bf(x1[1] * sc * wv[5]);
        o[6] = (short)f2bf(x1[2] * sc * wv[6]); o[7] = (short)f2bf(x1[3] * sc * wv[7]);
        int tok = tokbase0 + q * 64 + row;
        int hd = 2 * bx + hh;
        *(short8*)&dst[((size_t)hd * LEN + tok) * 128 + dloc] = o;
      }
    }
  } else {
    float* Lv = (float*)lds;                 // [256 d][68] f32 (col-major quarter)
#pragma unroll
    for (int q = 0; q < 4; ++q) {
      SBAR;
      if (wr == (q >> 1)) {
        const int amb = (q & 1) * 4;
#pragma unroll
        for (int am2 = 0; am2 < 4; ++am2)
#pragma unroll
          for (int n = 0; n < 4; ++n)
            *(f32x4*)&Lv[(wc * 64 + n * 16 + lr) * 68 + am2 * 16 + lg * 4] =
                acc[amb + am2][n];
      }
      SBAR;
      int d = tid >> 1, th = tid & 1;        // d 0..255, token half
      const float* src = &Lv[d * 68 + th * 32];
      int kh = (bx - 4) * 2 + (d >> 7);
      int tok = tokbase0 + q * 64 + th * 32;
      unsigned short* vp = &v_t[((size_t)kh * 128 + (d & 127)) * KVLEN + tok];
#pragma unroll
      for (int j = 0; j < 4; ++j) {
        f32x4 v0 = *(const f32x4*)(src + j * 8);
        f32x4 v1 = *(const f32x4*)(src + j * 8 + 4);
        short8 o;
        o[0] = (short)f2bf(v0[0]); o[1] = (short)f2bf(v0[1]);
        o[2] = (short)f2bf(v0[2]); o[3] = (short)f2bf(v0[3]);
        o[4] = (short)f2bf(v1[0]); o[5] = (short)f2bf(v1[1]);
        o[6] = (short)f2bf(v1[2]); o[7] = (short)f2bf(v1[3]);
        *(short8*)(vp + j * 8) = o;
      }
    }
  }
#undef STG4
#undef MM
}

// ---------------- attention: K/V chunk double-buffer, 1 barrier/chunk ----------------
__global__ __launch_bounds__(256, 4) void attn_kernel(
    const unsigned short* __restrict__ qb,   // [16][2048][128]
    const unsigned short* __restrict__ kb,   // [8][4096][128]
    const unsigned short* __restrict__ vt,   // [8][128][4096]
    const int* __restrict__ seq_lens,
    float* __restrict__ out) {               // [2048][2048]
  __shared__ __align__(16) char smem[73728];

  const int h = blockIdx.y;
  const int t0 = blockIdx.x * 64;
  int req = 0, qs = 0;
#pragma unroll 1
  while (req < NREQ - 1 && qs + seq_lens[req] <= t0) { qs += seq_lens[req]; ++req; }
  const int slen = seq_lens[req];
  const int rows = min(64, qs + slen - t0);
  if (rows <= 0) return;
  const int qbase = t0;

  const int tid = threadIdx.x, lane = tid & 63, wave = tid >> 6;
  const int lr = lane & 15, lg = lane >> 4;
  const int m0w = wave * 16;
  const int kh = h >> 1;
  const int kv0 = req * ENCLEN;

#define STAGE_K(c, db)                                                        \
  _Pragma("unroll") for (int i = 0; i < 4; ++i) {                             \
    int idx = i * 256 + tid;                                                  \
    int row = idx >> 4, slot = idx & 15;                                      \
    g2l16(kb + ((size_t)kh * KVLEN + kv0 + (c) * 64 + row) * 128 +            \
              ((slot ^ (row & 15)) << 3),                                     \
          smem + (db) * 16384 + idx * 16);                                    \
  }
#define STAGE_V(c, db)                                                        \
  _Pragma("unroll") for (int i = 0; i < 4; ++i) {                             \
    int idx = i * 256 + tid;                                                  \
    int row = idx >> 3, slot = idx & 7;                                       \
    g2l16(vt + ((size_t)kh * 128 + row) * KVLEN + kv0 + (c) * 64 +            \
              ((slot ^ (row & 7)) << 3),                                      \
          smem + 32768 + (db) * 16384 + idx * 16);                            \
  }

  unsigned short* Ps = (unsigned short*)(smem + 65536);

  short8 a_q[4];
  {
    int qr = qbase + min(m0w + lr, rows - 1);
    const unsigned short* qp = qb + ((size_t)h * QLEN + qr) * 128 + lg * 8;
#pragma unroll
    for (int ks = 0; ks < 4; ++ks) a_q[ks] = *(const short8*)(qp + ks * 32);
  }

  f32x4 acc[8] = {};
  float mrow[4], lsum[4];
#pragma unroll
  for (int r = 0; r < 4; ++r) { mrow[r] = -1e30f; lsum[r] = 0.f; }

  STAGE_K(0, 0); STAGE_V(0, 0);

  int cb = 0;
#pragma unroll 1
  for (int c = 0; c < 8; ++c) {
    asm volatile("s_waitcnt vmcnt(0)" ::: "memory");
    __syncthreads();
    if (c < 7) { STAGE_K(c + 1, cb ^ 1); STAGE_V(c + 1, cb ^ 1); }
    const unsigned short* Kb = (const unsigned short*)(smem + cb * 16384);
    const unsigned short* Vb = (const unsigned short*)(smem + 32768 + cb * 16384);

    f32x4 s[4] = {};
#pragma unroll
    for (int ks = 0; ks < 4; ++ks) {
      short8 bk[4];
#pragma unroll
      for (int n = 0; n < 4; ++n) {
        int row = n * 16 + lr;
        bk[n] = *(const short8*)&Kb[row * 128 + (((ks * 4 + lg) ^ (row & 15)) << 3)];
      }
#pragma unroll
      for (int n = 0; n < 4; ++n)
        s[n] = __builtin_amdgcn_mfma_f32_16x16x32_bf16(a_q[ks], bk[n], s[n], 0, 0, 0);
    }

#pragma unroll
    for (int r = 0; r < 4; ++r) {
      float mx = fmaxf(fmaxf(s[0][r], s[1][r]), fmaxf(s[2][r], s[3][r]));
#pragma unroll
      for (int msk = 8; msk >= 1; msk >>= 1) mx = fmaxf(mx, __shfl_xor(mx, msk));
      float mnew = fmaxf(mrow[r], mx);
      float al = __expf(mrow[r] - mnew);
      mrow[r] = mnew;
      float rs = 0.f;
#pragma unroll
      for (int n = 0; n < 4; ++n) {
        float p = __expf(s[n][r] - mnew);
        s[n][r] = p;
        rs += p;
      }
#pragma unroll
      for (int msk = 8; msk >= 1; msk >>= 1) rs += __shfl_xor(rs, msk);
      lsum[r] = lsum[r] * al + rs;
#pragma unroll
      for (int n2 = 0; n2 < 8; ++n2) acc[n2][r] *= al;
    }

#pragma unroll
    for (int n = 0; n < 4; ++n)
#pragma unroll
      for (int r = 0; r < 4; ++r) {
        int row = m0w + lg * 4 + r;
        int col = n * 16 + lr;
        Ps[row * 64 + (col ^ ((row & 7) << 3))] = f2bf(s[n][r]);
      }
    asm volatile("s_waitcnt lgkmcnt(0)" ::: "memory");
    __builtin_amdgcn_sched_barrier(0);

#pragma unroll
    for (int ks = 0; ks < 2; ++ks) {
      int prow = m0w + lr;
      short8 pa = *(const short8*)&Ps[prow * 64 + (((ks * 4 + lg) ^ (prow & 7)) << 3)];
#pragma unroll
      for (int n2 = 0; n2 < 8; ++n2) {
        int row = n2 * 16 + lr;
        short8 bv = *(const short8*)&Vb[row * 64 + (((ks * 4 + lg) ^ (row & 7)) << 3)];
        acc[n2] = __builtin_amdgcn_mfma_f32_16x16x32_bf16(pa, bv, acc[n2], 0, 0, 0);
      }
    }
    cb ^= 1;
  }
  __syncthreads();

  float inv[4];
#pragma unroll
  for (int r = 0; r < 4; ++r) inv[r] = 1.0f / lsum[r];
#pragma unroll
  for (int n2 = 0; n2 < 8; ++n2)
#pragma unroll
    for (int r = 0; r < 4; ++r) acc[n2][r] *= inv[r];

  constexpr int OFS = 132;
  float* Of = (float*)smem;
#pragma unroll
  for (int n2 = 0; n2 < 8; ++n2)
#pragma unroll
    for (int r = 0; r < 4; ++r)
      Of[(m0w + lg * 4 + r) * OFS + n2 * 16 + lr] = acc[n2][r];
  __syncthreads();
#pragma unroll
  for (int p = 0; p < 8; ++p) {
    int idx = p * 256 + tid;
    int row = idx >> 5, c4 = (idx & 31) * 4;
    if (row < rows) {
      f32x4 v = *(const f32x4*)&Of[row * OFS + c4];
      *(f32x4*)&out[(size_t)(qbase + row) * 2048 + h * 128 + c4] = v;
    }
  }
#undef STAGE_K
#undef STAGE_V
}

// ---------------- launch ----------------
extern "C" void kernel_launch(void* const* d_in, const int* in_sizes, int n_in,
                              void* d_out, int out_size, void* d_ws, size_t ws_size,
                              hipStream_t stream) {
  const float* hidden = (const float*)d_in[0];
  const float* enc    = (const float*)d_in[1];
  const float* w_qkv  = (const float*)d_in[2];
  const float* q_nw   = (const float*)d_in[3];
  const float* k_nw   = (const float*)d_in[4];
  const int*   slens  = (const int*)d_in[5];
  float* out = (float*)d_out;

  char* ws = (char*)d_ws;
  unsigned short* h_bf = (unsigned short*)(ws + 0);           //  8.39 MB
  unsigned short* e_bf = (unsigned short*)(ws + 8388608);     // 16.78 MB
  unsigned short* w_bf = (unsigned short*)(ws + 25165824);    // 16.78 MB
  unsigned short* q_bf = (unsigned short*)(ws + 41943040);    //  8.39 MB
  unsigned short* k_bf = (unsigned short*)(ws + 50331648);    //  8.39 MB
  unsigned short* v_t  = (unsigned short*)(ws + 58720256);    //  8.39 MB (ends 67.1MB)

  static bool attr_set = false;
  if (!attr_set) {
    hipFuncSetAttribute((const void*)gemm_qkv8,
                        hipFuncAttributeMaxDynamicSharedMemorySize, 131072);
    attr_set = true;
  }

  cvt_all<<<10240, 256, 0, stream>>>(hidden, enc, w_qkv, h_bf, e_bf, w_bf);

  gemm_qkv8<<<dim3(8, 24), 512, 131072, stream>>>(h_bf, e_bf, w_bf, q_nw, k_nw,
                                                  q_bf, k_bf, v_t);

  attn_kernel<<<dim3(32, 16), 256, 0, stream>>>(q_bf, k_bf, v_t, slens, out);
}